// Round 9
// baseline (180.438 us; speedup 1.0000x reference)
//
#include <hip/hip_runtime.h>
#include <hip/hip_bf16.h>

#define NB 16
#define NN 512
#define ND 512
#define NH 8

using short8 = __attribute__((ext_vector_type(8))) short;
using f32x4  = __attribute__((ext_vector_type(4))) float;
using int4v  = __attribute__((ext_vector_type(4))) int;

static __device__ __forceinline__ unsigned short f2bf(float f) {
  unsigned u = __builtin_bit_cast(unsigned, f);
  unsigned r = 0x7fffu + ((u >> 16) & 1u);
  return (unsigned short)((u + r) >> 16);
}
static __device__ __forceinline__ float bf2f(unsigned short u) {
  return __builtin_bit_cast(float, (unsigned)u << 16);
}

// ---------------------------------------------------------------- kernel 0
// Transpose 4 weight mats [k][n] fp32 -> [n][k] bf16 (Wq,Wk,Wv,Wo)
__global__ __launch_bounds__(256) void wprep(
    const float* __restrict__ Wq, const float* __restrict__ Wk,
    const float* __restrict__ Wv, const float* __restrict__ Wo,
    unsigned short* __restrict__ T) {
  const float* W;
  switch (blockIdx.z) {
    case 0: W = Wq; break;
    case 1: W = Wk; break;
    case 2: W = Wv; break;
    default: W = Wo; break;
  }
  unsigned short* Wt = T + (size_t)blockIdx.z * 512 * 512;
  __shared__ float tile[64][65];
  const int t = threadIdx.x;
  const int k0 = blockIdx.x * 64, n0 = blockIdx.y * 64;
#pragma unroll
  for (int it = 0; it < 4; ++it) {
    int row = it * 16 + (t >> 4);
    int c4 = (t & 15) * 4;
    float4 v = *(const float4*)&W[(size_t)(k0 + row) * 512 + n0 + c4];
    tile[row][c4] = v.x; tile[row][c4 + 1] = v.y;
    tile[row][c4 + 2] = v.z; tile[row][c4 + 3] = v.w;
  }
  __syncthreads();
#pragma unroll
  for (int it = 0; it < 4; ++it) {
    int nr = it * 16 + (t >> 4);
    int k4 = (t & 15) * 4;
    ushort4 o;
    o.x = f2bf(tile[k4 + 0][nr]); o.y = f2bf(tile[k4 + 1][nr]);
    o.z = f2bf(tile[k4 + 2][nr]); o.w = f2bf(tile[k4 + 3][nr]);
    *(ushort4*)&Wt[(size_t)(n0 + nr) * 512 + k0 + k4] = o;
  }
}

// ---------------------------------------------------------------- kernel 1
// QKV projection: X[8192x512]fp32 @ Wt^T + b -> bf16, scattered to
// q_ws/k_ws [B,H,N,64], vt_ws [B,H,64,N]
__global__ __launch_bounds__(256) void qkv_gemm(
    const float* __restrict__ Xq, const float* __restrict__ Xk,
    const float* __restrict__ Xv, const unsigned short* __restrict__ Wt,
    const float* __restrict__ bq, const float* __restrict__ bk,
    const float* __restrict__ bv, unsigned short* __restrict__ q_ws,
    unsigned short* __restrict__ k_ws, unsigned short* __restrict__ vt_ws) {
  const int zi = blockIdx.z;
  const float* X = (zi == 0) ? Xq : (zi == 1) ? Xk : Xv;
  const unsigned short* Wz = Wt + (size_t)zi * 512 * 512;
  const float* bias = (zi == 0) ? bq : (zi == 1) ? bk : bv;
  const int m0 = blockIdx.x * 128, n0 = blockIdx.y * 128;
  __shared__ unsigned short Al[2][128][40];
  __shared__ unsigned short Bl[2][128][40];
  const int t = threadIdx.x;
  const int w = t >> 6, l = t & 63;
  const int lr = l & 15, lg = l >> 4;
  const int wr = (w >> 1) * 64, wc = (w & 1) * 64;
  f32x4 acc[4][4] = {};
  for (int kk = 0; kk < 512; kk += 64) {
    __syncthreads();
    {
      const int colk = (t & 15) * 4;
      const int kc = colk >> 5, kin = colk & 31;
#pragma unroll
      for (int p = 0; p < 8; ++p) {
        int row = p * 16 + (t >> 4);
        float4 v = *(const float4*)&X[(size_t)(m0 + row) * 512 + kk + colk];
        ushort4 o;
        o.x = f2bf(v.x); o.y = f2bf(v.y); o.z = f2bf(v.z); o.w = f2bf(v.w);
        *(ushort4*)&Al[kc][row][kin] = o;
      }
      const int colk8 = (t & 7) * 8;
      const int kc2 = colk8 >> 5, kin2 = colk8 & 31;
#pragma unroll
      for (int p = 0; p < 4; ++p) {
        int row = p * 32 + (t >> 3);
        short8 v = *(const short8*)&Wz[(size_t)(n0 + row) * 512 + kk + colk8];
        *(short8*)&Bl[kc2][row][kin2] = v;
      }
    }
    __syncthreads();
#pragma unroll
    for (int kc = 0; kc < 2; ++kc) {
      short8 a[4], b[4];
      const int lk = lg * 8;
#pragma unroll
      for (int i = 0; i < 4; ++i) a[i] = *(const short8*)&Al[kc][wr + i * 16 + lr][lk];
#pragma unroll
      for (int i = 0; i < 4; ++i) b[i] = *(const short8*)&Bl[kc][wc + i * 16 + lr][lk];
#pragma unroll
      for (int i = 0; i < 4; ++i)
#pragma unroll
        for (int j = 0; j < 4; ++j)
          acc[i][j] = __builtin_amdgcn_mfma_f32_16x16x32_bf16(a[i], b[j], acc[i][j], 0, 0, 0);
    }
  }
#pragma unroll
  for (int j = 0; j < 4; ++j) {
    const int col = n0 + wc + j * 16 + lr;
    const float bb = bias[col];
    const int hh = col >> 6, dv = col & 63;
#pragma unroll
    for (int i = 0; i < 4; ++i) {
      const int mbase = m0 + wr + i * 16 + lg * 4;
      const int b_ = mbase >> 9, nt = mbase & 511;
      if (zi == 2) {
        ushort4 o;
        o.x = f2bf(acc[i][j][0] + bb); o.y = f2bf(acc[i][j][1] + bb);
        o.z = f2bf(acc[i][j][2] + bb); o.w = f2bf(acc[i][j][3] + bb);
        *(ushort4*)&vt_ws[((size_t)(b_ * NH + hh) * 64 + dv) * 512 + nt] = o;
      } else {
        unsigned short* dst = (zi == 0) ? q_ws : k_ws;
#pragma unroll
        for (int r = 0; r < 4; ++r)
          dst[((size_t)(b_ * NH + hh) * 512 + nt + r) * 64 + dv] = f2bf(acc[i][j][r] + bb);
      }
    }
  }
}

// ---------------------------------------------------------------- kernel 2
// Attention v9 — wave-independent, zero-LDS, zero-barrier, NO-SPILL:
//   launch_bounds(256,3) -> VGPR ceiling 170 so Ppk[32][2] (64 regs) stays
//   resident. Explicit 2-stage register pipeline in every phase: load group
//   g+1 (6x1KB for pass1; 4x1KB pass2; 4x1KB PV) while computing group g.
//   12 waves/CU, each with 6-12KB in flight most of its life.
//   Wave->tile map keeps all 32 q-tiles of one bh on one XCD (R8 FETCH win).
__global__ __launch_bounds__(256, 3) void attn_kernel(
    const unsigned short* __restrict__ q_ws, const unsigned short* __restrict__ k_ws,
    const unsigned short* __restrict__ vt_ws, const float* __restrict__ box,
    const float* __restrict__ Ext, unsigned short* __restrict__ hidden) {
  const int t = threadIdx.x;
  const int w = t >> 6, l = t & 63;
  const int lr = l & 15, lg = l >> 4;
  const int tile = blockIdx.x * 4 + w;
  const int bh = tile & 127;  // all 32 tiles of a bh land on one XCD
  const int q0 = (tile >> 7) * 16;
  const int b = bh >> 3, h = bh & 7;

  const unsigned short* Qp = q_ws + (size_t)bh * 512 * 64;
  const unsigned short* Kp = k_ws + (size_t)bh * 512 * 64;
  const unsigned short* Vt = vt_ws + (size_t)bh * 64 * 512;
  const float* boxp = box + ((size_t)bh * 512 + q0) * 512;
  const float* Ep = Ext + ((size_t)bh * 512 + q0) * 512;

  // Q fragments (B operand), q-col = lr
  short8 qf0 = *(const short8*)&Qp[(size_t)(q0 + lr) * 64 + lg * 8];
  short8 qf1 = *(const short8*)&Qp[(size_t)(q0 + lr) * 64 + 32 + lg * 8];

  // P packed bf16: chunk c (16 keys), lane holds keys c*16+lg*4+[0..3]
  unsigned Ppk[32][2];

  // ======== pass1: e1 = clip(box)*exp(att/8) -> Ppk; row sum ========
  // group = 2 chunks; A/B register double-buffer, pipeline depth 2.
  float s1 = 0.f;
  short8 kA0, kA1, kA2, kA3, kB0, kB1, kB2, kB3;
  f32x4 bA0, bA1, bB0, bB1;
#define LD_P1(K0, K1, K2, K3, B0, B1, c)                                   \
  do {                                                                     \
    K0 = *(const short8*)&Kp[(size_t)((c) * 16 + lr) * 64 + lg * 8];       \
    K1 = *(const short8*)&Kp[(size_t)((c) * 16 + lr) * 64 + 32 + lg * 8];  \
    K2 = *(const short8*)&Kp[(size_t)((c + 1) * 16 + lr) * 64 + lg * 8];   \
    K3 = *(const short8*)&Kp[(size_t)((c + 1) * 16 + lr) * 64 + 32 + lg * 8]; \
    B0 = *(const f32x4*)&boxp[(size_t)lr * 512 + (c) * 16 + lg * 4];       \
    B1 = *(const f32x4*)&boxp[(size_t)lr * 512 + (c + 1) * 16 + lg * 4];   \
  } while (0)
#define CMP_P1(K0, K1, K2, K3, B0, B1, c)                                  \
  do {                                                                     \
    f32x4 a0 = {0.f, 0.f, 0.f, 0.f}, a1 = {0.f, 0.f, 0.f, 0.f};           \
    a0 = __builtin_amdgcn_mfma_f32_16x16x32_bf16(K0, qf0, a0, 0, 0, 0);    \
    a0 = __builtin_amdgcn_mfma_f32_16x16x32_bf16(K1, qf1, a0, 0, 0, 0);    \
    a1 = __builtin_amdgcn_mfma_f32_16x16x32_bf16(K2, qf0, a1, 0, 0, 0);    \
    a1 = __builtin_amdgcn_mfma_f32_16x16x32_bf16(K3, qf1, a1, 0, 0, 0);    \
    float e0 = fmaxf(B0[0], 1e-6f) * __expf(a0[0] * 0.125f);               \
    float e1 = fmaxf(B0[1], 1e-6f) * __expf(a0[1] * 0.125f);               \
    float e2 = fmaxf(B0[2], 1e-6f) * __expf(a0[2] * 0.125f);               \
    float e3 = fmaxf(B0[3], 1e-6f) * __expf(a0[3] * 0.125f);               \
    float f0 = fmaxf(B1[0], 1e-6f) * __expf(a1[0] * 0.125f);               \
    float f1 = fmaxf(B1[1], 1e-6f) * __expf(a1[1] * 0.125f);               \
    float f2 = fmaxf(B1[2], 1e-6f) * __expf(a1[2] * 0.125f);               \
    float f3 = fmaxf(B1[3], 1e-6f) * __expf(a1[3] * 0.125f);               \
    s1 += ((e0 + e1) + (e2 + e3)) + ((f0 + f1) + (f2 + f3));               \
    Ppk[c][0] = ((unsigned)f2bf(e1) << 16) | f2bf(e0);                     \
    Ppk[c][1] = ((unsigned)f2bf(e3) << 16) | f2bf(e2);                     \
    Ppk[c + 1][0] = ((unsigned)f2bf(f1) << 16) | f2bf(f0);                 \
    Ppk[c + 1][1] = ((unsigned)f2bf(f3) << 16) | f2bf(f2);                 \
  } while (0)
  LD_P1(kA0, kA1, kA2, kA3, bA0, bA1, 0);
#pragma unroll
  for (int g = 0; g < 8; ++g) {
    LD_P1(kB0, kB1, kB2, kB3, bB0, bB1, g * 4 + 2);
    CMP_P1(kA0, kA1, kA2, kA3, bA0, bA1, g * 4);
    if (g < 7) LD_P1(kA0, kA1, kA2, kA3, bA0, bA1, g * 4 + 4);
    CMP_P1(kB0, kB1, kB2, kB3, bB0, bB1, g * 4 + 2);
  }
  s1 += __shfl_xor(s1, 16);
  s1 += __shfl_xor(s1, 32);
  const float l1i = 1.0f / s1;  // row lr sum (wave covers all 512 keys)

  // ======== pass2: P = exp(e1*l1i + Ext) -> Ppk; row sum ========
  // group = 4 chunks (4x f32x4 Ext loads), A/B double-buffer.
  float s2 = 0.f;
  f32x4 eA0, eA1, eA2, eA3, eB0, eB1, eB2, eB3;
#define LD_P2(E0, E1, E2, E3, c)                                           \
  do {                                                                     \
    E0 = *(const f32x4*)&Ep[(size_t)lr * 512 + (c) * 16 + lg * 4];         \
    E1 = *(const f32x4*)&Ep[(size_t)lr * 512 + (c + 1) * 16 + lg * 4];     \
    E2 = *(const f32x4*)&Ep[(size_t)lr * 512 + (c + 2) * 16 + lg * 4];     \
    E3 = *(const f32x4*)&Ep[(size_t)lr * 512 + (c + 3) * 16 + lg * 4];     \
  } while (0)
#define CMP1_P2(E, c)                                                      \
  do {                                                                     \
    float p0 = __expf(bf2f((unsigned short)(Ppk[c][0] & 0xffff)) * l1i + E[0]); \
    float p1 = __expf(bf2f((unsigned short)(Ppk[c][0] >> 16)) * l1i + E[1]);    \
    float p2 = __expf(bf2f((unsigned short)(Ppk[c][1] & 0xffff)) * l1i + E[2]); \
    float p3 = __expf(bf2f((unsigned short)(Ppk[c][1] >> 16)) * l1i + E[3]);    \
    s2 += (p0 + p1) + (p2 + p3);                                           \
    Ppk[c][0] = ((unsigned)f2bf(p1) << 16) | f2bf(p0);                     \
    Ppk[c][1] = ((unsigned)f2bf(p3) << 16) | f2bf(p2);                     \
  } while (0)
  LD_P2(eA0, eA1, eA2, eA3, 0);
#pragma unroll
  for (int g = 0; g < 4; ++g) {
    LD_P2(eB0, eB1, eB2, eB3, g * 8 + 4);
    CMP1_P2(eA0, g * 8 + 0); CMP1_P2(eA1, g * 8 + 1);
    CMP1_P2(eA2, g * 8 + 2); CMP1_P2(eA3, g * 8 + 3);
    if (g < 3) LD_P2(eA0, eA1, eA2, eA3, g * 8 + 8);
    CMP1_P2(eB0, g * 8 + 4); CMP1_P2(eB1, g * 8 + 5);
    CMP1_P2(eB2, g * 8 + 6); CMP1_P2(eB3, g * 8 + 7);
  }
  s2 += __shfl_xor(s2, 16);
  s2 += __shfl_xor(s2, 32);

  // 1/l2 for this thread's OUTPUT rows (q = lg*4+r)
  float l2v[4];
#pragma unroll
  for (int r = 0; r < 4; ++r) l2v[r] = 1.0f / __shfl(s2, lg * 4 + r);

  // ======== PV: in-register repack (shfl) + MFMA, V double-buffered ======
  const int src0 = (2 * (lg & 1)) * 16 + lr;
  const int src1 = src0 + 16;
  const bool hi = ((lg >> 1) & 1) != 0;
  f32x4 o4[4] = {};
  short8 vA0, vA1, vA2, vA3, vB0, vB1, vB2, vB3;
#define LD_PV(V0, V1, V2, V3, kc)                                          \
  do {                                                                     \
    V0 = *(const short8*)&Vt[(size_t)(0 * 16 + lr) * 512 + (kc) * 32 + lg * 8]; \
    V1 = *(const short8*)&Vt[(size_t)(1 * 16 + lr) * 512 + (kc) * 32 + lg * 8]; \
    V2 = *(const short8*)&Vt[(size_t)(2 * 16 + lr) * 512 + (kc) * 32 + lg * 8]; \
    V3 = *(const short8*)&Vt[(size_t)(3 * 16 + lr) * 512 + (kc) * 32 + lg * 8]; \
  } while (0)
#define CMP_PV(V0, V1, V2, V3, kc)                                         \
  do {                                                                     \
    const int a0 = __shfl((int)Ppk[2 * (kc)][0], src0);                    \
    const int b0 = __shfl((int)Ppk[2 * (kc) + 1][0], src0);                \
    const int a1 = __shfl((int)Ppk[2 * (kc)][1], src0);                    \
    const int b1 = __shfl((int)Ppk[2 * (kc) + 1][1], src0);                \
    const int a2 = __shfl((int)Ppk[2 * (kc)][0], src1);                    \
    const int b2 = __shfl((int)Ppk[2 * (kc) + 1][0], src1);                \
    const int a3 = __shfl((int)Ppk[2 * (kc)][1], src1);                    \
    const int b3 = __shfl((int)Ppk[2 * (kc) + 1][1], src1);                \
    int4v pu;                                                              \
    pu[0] = hi ? b0 : a0; pu[1] = hi ? b1 : a1;                            \
    pu[2] = hi ? b2 : a2; pu[3] = hi ? b3 : a3;                            \
    short8 pa = __builtin_bit_cast(short8, pu);                            \
    o4[0] = __builtin_amdgcn_mfma_f32_16x16x32_bf16(pa, V0, o4[0], 0, 0, 0); \
    o4[1] = __builtin_amdgcn_mfma_f32_16x16x32_bf16(pa, V1, o4[1], 0, 0, 0); \
    o4[2] = __builtin_amdgcn_mfma_f32_16x16x32_bf16(pa, V2, o4[2], 0, 0, 0); \
    o4[3] = __builtin_amdgcn_mfma_f32_16x16x32_bf16(pa, V3, o4[3], 0, 0, 0); \
  } while (0)
  LD_PV(vA0, vA1, vA2, vA3, 0);
#pragma unroll
  for (int g = 0; g < 8; ++g) {
    LD_PV(vB0, vB1, vB2, vB3, g * 2 + 1);
    CMP_PV(vA0, vA1, vA2, vA3, g * 2);
    if (g < 7) LD_PV(vA0, vA1, vA2, vA3, g * 2 + 2);
    CMP_PV(vB0, vB1, vB2, vB3, g * 2 + 1);
  }
  // ---- scale + store (rows q0+lg*4+r, cols h*64+c2*16+lr) ----
#pragma unroll
  for (int c2 = 0; c2 < 4; ++c2)
#pragma unroll
    for (int r = 0; r < 4; ++r)
      hidden[(size_t)(b * 512 + q0 + lg * 4 + r) * 512 + h * 64 + c2 * 16 + lr] =
          f2bf(o4[c2][r] * l2v[r]);
#undef LD_P1
#undef CMP_P1
#undef LD_P2
#undef CMP1_P2
#undef LD_PV
#undef CMP_PV
}

// ---------------------------------------------------------------- kernel 3
// out = hidden[8192x512]bf16 @ WoT + bo  (fp32 out)
__global__ __launch_bounds__(256) void out_gemm(
    const unsigned short* __restrict__ hidden, const unsigned short* __restrict__ WoT,
    const float* __restrict__ bo, float* __restrict__ out) {
  const int m0 = blockIdx.x * 128, n0 = blockIdx.y * 128;
  __shared__ unsigned short Al[2][128][40];
  __shared__ unsigned short Bl[2][128][40];
  const int t = threadIdx.x;
  const int w = t >> 6, l = t & 63;
  const int lr = l & 15, lg = l >> 4;
  const int wr = (w >> 1) * 64, wc = (w & 1) * 64;
  f32x4 acc[4][4] = {};
  for (int kk = 0; kk < 512; kk += 64) {
    __syncthreads();
    {
      const int colk8 = (t & 7) * 8;
      const int kc2 = colk8 >> 5, kin2 = colk8 & 31;
#pragma unroll
      for (int p = 0; p < 4; ++p) {
        int row = p * 32 + (t >> 3);
        short8 v = *(const short8*)&hidden[(size_t)(m0 + row) * 512 + kk + colk8];
        *(short8*)&Al[kc2][row][kin2] = v;
      }
#pragma unroll
      for (int p = 0; p < 4; ++p) {
        int row = p * 32 + (t >> 3);
        short8 v = *(const short8*)&WoT[(size_t)(n0 + row) * 512 + kk + colk8];
        *(short8*)&Bl[kc2][row][kin2] = v;
      }
    }
    __syncthreads();
#pragma unroll
    for (int kc = 0; kc < 2; ++kc) {
      short8 a[4], b[4];
      const int lk = lg * 8;
#pragma unroll
      for (int i = 0; i < 4; ++i) a[i] = *(const short8*)&Al[kc][wr + i * 16 + lr][lk];
#pragma unroll
      for (int i = 0; i < 4; ++i) b[i] = *(const short8*)&Bl[kc][wc + i * 16 + lr][lk];
#pragma unroll
      for (int i = 0; i < 4; ++i)
#pragma unroll
        for (int j = 0; j < 4; ++j)
          acc[i][j] = __builtin_amdgcn_mfma_f32_16x16x32_bf16(a[i], b[j], acc[i][j], 0, 0, 0);
    }
  }
#pragma unroll
  for (int j = 0; j < 4; ++j) {
    const int col = n0 + wc + j * 16 + lr;
    const float bb = bo[col];
#pragma unroll
    for (int i = 0; i < 4; ++i)
#pragma unroll
      for (int r = 0; r < 4; ++r)
        out[(size_t)(m0 + wr + i * 16 + lg * 4 + r) * 512 + col] = acc[i][j][r] + bb;
  }
}

// ---------------------------------------------------------------- launch
extern "C" void kernel_launch(void* const* d_in, const int* in_sizes, int n_in,
                              void* d_out, int out_size, void* d_ws, size_t ws_size,
                              hipStream_t stream) {
  const float* queries = (const float*)d_in[0];
  const float* keys = (const float*)d_in[1];
  const float* values = (const float*)d_in[2];
  const float* box = (const float*)d_in[3];
  const float* ext = (const float*)d_in[4];
  const float* Wq = (const float*)d_in[5];
  const float* bq = (const float*)d_in[6];
  const float* Wk = (const float*)d_in[7];
  const float* bk = (const float*)d_in[8];
  const float* Wv = (const float*)d_in[9];
  const float* bv = (const float*)d_in[10];
  const float* Wo = (const float*)d_in[11];
  const float* bo = (const float*)d_in[12];
  float* out = (float*)d_out;

  char* ws = (char*)d_ws;
  unsigned short* q_ws = (unsigned short*)(ws);
  unsigned short* k_ws = (unsigned short*)(ws + 8u * 1024 * 1024);
  unsigned short* vt_ws = (unsigned short*)(ws + 16u * 1024 * 1024);
  unsigned short* hidden = (unsigned short*)(ws + 24u * 1024 * 1024);
  unsigned short* wt = (unsigned short*)(ws + 32u * 1024 * 1024);  // 4 x 512KB

  wprep<<<dim3(8, 8, 4), 256, 0, stream>>>(Wq, Wk, Wv, Wo, wt);
  qkv_gemm<<<dim3(64, 4, 3), 256, 0, stream>>>(queries, keys, values, wt, bq, bk, bv,
                                               q_ws, k_ws, vt_ws);
  attn_kernel<<<dim3(1024), 256, 0, stream>>>(q_ws, k_ws, vt_ws, box, ext, hidden);
  out_gemm<<<dim3(64, 4), 256, 0, stream>>>(hidden, wt + 3u * 512 * 512, bo, out);
}

// Round 11
// 165.831 us; speedup vs baseline: 1.0881x; 1.0881x over previous
//
#include <hip/hip_runtime.h>
#include <hip/hip_bf16.h>

#define NB 16
#define NN 512
#define ND 512
#define NH 8

using short8 = __attribute__((ext_vector_type(8))) short;
using f32x4  = __attribute__((ext_vector_type(4))) float;

static __device__ __forceinline__ unsigned short f2bf(float f) {
  unsigned u = __builtin_bit_cast(unsigned, f);
  unsigned r = 0x7fffu + ((u >> 16) & 1u);
  return (unsigned short)((u + r) >> 16);
}

// inline-asm 16B load: compiler cannot sink, split, or spill the request
#define LDX(dst, base, offlit)                                          \
  asm volatile("global_load_dwordx4 %0, %1, off" offlit                 \
               : "=v"(dst) : "v"(base) : "memory")

// ---------------------------------------------------------------- kernel 0
// Transpose 4 weight mats [k][n] fp32 -> [n][k] bf16 (Wq,Wk,Wv,Wo)
__global__ __launch_bounds__(256) void wprep(
    const float* __restrict__ Wq, const float* __restrict__ Wk,
    const float* __restrict__ Wv, const float* __restrict__ Wo,
    unsigned short* __restrict__ T) {
  const float* W;
  switch (blockIdx.z) {
    case 0: W = Wq; break;
    case 1: W = Wk; break;
    case 2: W = Wv; break;
    default: W = Wo; break;
  }
  unsigned short* Wt = T + (size_t)blockIdx.z * 512 * 512;
  __shared__ float tile[64][65];
  const int t = threadIdx.x;
  const int k0 = blockIdx.x * 64, n0 = blockIdx.y * 64;
#pragma unroll
  for (int it = 0; it < 4; ++it) {
    int row = it * 16 + (t >> 4);
    int c4 = (t & 15) * 4;
    float4 v = *(const float4*)&W[(size_t)(k0 + row) * 512 + n0 + c4];
    tile[row][c4] = v.x; tile[row][c4 + 1] = v.y;
    tile[row][c4 + 2] = v.z; tile[row][c4 + 3] = v.w;
  }
  __syncthreads();
#pragma unroll
  for (int it = 0; it < 4; ++it) {
    int nr = it * 16 + (t >> 4);
    int k4 = (t & 15) * 4;
    ushort4 o;
    o.x = f2bf(tile[k4 + 0][nr]); o.y = f2bf(tile[k4 + 1][nr]);
    o.z = f2bf(tile[k4 + 2][nr]); o.w = f2bf(tile[k4 + 3][nr]);
    *(ushort4*)&Wt[(size_t)(n0 + nr) * 512 + k0 + k4] = o;
  }
}

// ---------------------------------------------------------------- kernel 1
// QKV projection: X[8192x512]fp32 @ Wt^T + b -> bf16, scattered to
// q_ws/k_ws [B,H,N,64], vt_ws [B,H,64,N]
__global__ __launch_bounds__(256) void qkv_gemm(
    const float* __restrict__ Xq, const float* __restrict__ Xk,
    const float* __restrict__ Xv, const unsigned short* __restrict__ Wt,
    const float* __restrict__ bq, const float* __restrict__ bk,
    const float* __restrict__ bv, unsigned short* __restrict__ q_ws,
    unsigned short* __restrict__ k_ws, unsigned short* __restrict__ vt_ws) {
  const int zi = blockIdx.z;
  const float* X = (zi == 0) ? Xq : (zi == 1) ? Xk : Xv;
  const unsigned short* Wz = Wt + (size_t)zi * 512 * 512;
  const float* bias = (zi == 0) ? bq : (zi == 1) ? bk : bv;
  const int m0 = blockIdx.x * 128, n0 = blockIdx.y * 128;
  __shared__ unsigned short Al[2][128][40];
  __shared__ unsigned short Bl[2][128][40];
  const int t = threadIdx.x;
  const int w = t >> 6, l = t & 63;
  const int lr = l & 15, lg = l >> 4;
  const int wr = (w >> 1) * 64, wc = (w & 1) * 64;
  f32x4 acc[4][4] = {};
  for (int kk = 0; kk < 512; kk += 64) {
    __syncthreads();
    {
      const int colk = (t & 15) * 4;
      const int kc = colk >> 5, kin = colk & 31;
#pragma unroll
      for (int p = 0; p < 8; ++p) {
        int row = p * 16 + (t >> 4);
        float4 v = *(const float4*)&X[(size_t)(m0 + row) * 512 + kk + colk];
        ushort4 o;
        o.x = f2bf(v.x); o.y = f2bf(v.y); o.z = f2bf(v.z); o.w = f2bf(v.w);
        *(ushort4*)&Al[kc][row][kin] = o;
      }
      const int colk8 = (t & 7) * 8;
      const int kc2 = colk8 >> 5, kin2 = colk8 & 31;
#pragma unroll
      for (int p = 0; p < 4; ++p) {
        int row = p * 32 + (t >> 3);
        short8 v = *(const short8*)&Wz[(size_t)(n0 + row) * 512 + kk + colk8];
        *(short8*)&Bl[kc2][row][kin2] = v;
      }
    }
    __syncthreads();
#pragma unroll
    for (int kc = 0; kc < 2; ++kc) {
      short8 a[4], b[4];
      const int lk = lg * 8;
#pragma unroll
      for (int i = 0; i < 4; ++i) a[i] = *(const short8*)&Al[kc][wr + i * 16 + lr][lk];
#pragma unroll
      for (int i = 0; i < 4; ++i) b[i] = *(const short8*)&Bl[kc][wc + i * 16 + lr][lk];
#pragma unroll
      for (int i = 0; i < 4; ++i)
#pragma unroll
        for (int j = 0; j < 4; ++j)
          acc[i][j] = __builtin_amdgcn_mfma_f32_16x16x32_bf16(a[i], b[j], acc[i][j], 0, 0, 0);
    }
  }
#pragma unroll
  for (int j = 0; j < 4; ++j) {
    const int col = n0 + wc + j * 16 + lr;
    const float bb = bias[col];
    const int hh = col >> 6, dv = col & 63;
#pragma unroll
    for (int i = 0; i < 4; ++i) {
      const int mbase = m0 + wr + i * 16 + lg * 4;
      const int b_ = mbase >> 9, nt = mbase & 511;
      if (zi == 2) {
        ushort4 o;
        o.x = f2bf(acc[i][j][0] + bb); o.y = f2bf(acc[i][j][1] + bb);
        o.z = f2bf(acc[i][j][2] + bb); o.w = f2bf(acc[i][j][3] + bb);
        *(ushort4*)&vt_ws[((size_t)(b_ * NH + hh) * 64 + dv) * 512 + nt] = o;
      } else {
        unsigned short* dst = (zi == 0) ? q_ws : k_ws;
#pragma unroll
        for (int r = 0; r < 4; ++r)
          dst[((size_t)(b_ * NH + hh) * 512 + nt + r) * 64 + dv] = f2bf(acc[i][j][r] + bb);
      }
    }
  }
}

// ---------------------------------------------------------------- kernel 2
// Attention v11 — v4 numerics (z fp32 through both passes, ONE bf16
// rounding at normalized P) + asm-burst MLP:
//   16 q-rows/block, 4 waves x 128 keys. Entry: preload kf[8][2] (compiler)
//   + 8 box LDX (asm) -> ~26KB issued back-to-back per wave; ONE explicit
//   vmcnt(0)+sched_barrier(0) drain; pure-compute pass1. Ext burst (8 LDX)
//   issued before the sum1 barrier, drained vmcnt(0)+sched_barrier after it.
//   Raw s_barrier+lgkmcnt(0) (Ext stays in flight across barrier).
//   XCD mapping keeps each bh's 32 q-tiles on one XCD (R7 FETCH win).
__global__ __launch_bounds__(256, 3) void attn_kernel(
    const unsigned short* __restrict__ q_ws, const unsigned short* __restrict__ k_ws,
    const unsigned short* __restrict__ vt_ws, const float* __restrict__ box,
    const float* __restrict__ Ext, unsigned short* __restrict__ hidden) {
  const int t = threadIdx.x;
  const int w = t >> 6, l = t & 63;
  const int lr = l & 15, lg = l >> 4;
  const int wg = blockIdx.x;
  const int xcd = wg & 7, slot = wg >> 3;
  const int bh = xcd + 8 * (slot >> 5);  // all 32 q-tiles of bh -> one XCD
  const int q0 = (slot & 31) * 16;
  const int b = bh >> 3, h = bh & 7;

  const unsigned short* Qp = q_ws + (size_t)bh * 512 * 64;
  const unsigned short* Kp = k_ws + (size_t)bh * 512 * 64;
  const unsigned short* Vt = vt_ws + (size_t)bh * 64 * 512;
  const float* boxp = box + ((size_t)bh * 512 + q0) * 512;
  const float* Ep = Ext + ((size_t)bh * 512 + q0) * 512;

  __shared__ float red[4][16];
  __shared__ float red2[4][16];
  // per-wave: P bf16 [16][144] (4608B); out f32 [16][68] (4352B) aliases
  __shared__ __align__(16) unsigned char wsh[4][4608];

  const int n0w = w * 128;
  unsigned short(*Pw)[144] = (unsigned short(*)[144])wsh[w];

  // ---- box burst: 8 asm dwordx4 (8KB/wave), issued first ----
  f32x4 bx[8];
  {
    const float* bp = boxp + (size_t)lr * 512 + n0w + lg * 4;
    LDX(bx[0], bp, "");
    LDX(bx[1], bp, " offset:64");
    LDX(bx[2], bp, " offset:128");
    LDX(bx[3], bp, " offset:192");
    LDX(bx[4], bp, " offset:256");
    LDX(bx[5], bp, " offset:320");
    LDX(bx[6], bp, " offset:384");
    LDX(bx[7], bp, " offset:448");
  }
  // Q fragments + all K fragments (compiler loads, issued into same window)
  short8 qf0 = *(const short8*)&Qp[(size_t)(q0 + lr) * 64 + lg * 8];
  short8 qf1 = *(const short8*)&Qp[(size_t)(q0 + lr) * 64 + 32 + lg * 8];
  short8 kf[8][2];
#pragma unroll
  for (int c = 0; c < 8; ++c) {
    const int krow = n0w + c * 16 + lr;
    kf[c][0] = *(const short8*)&Kp[(size_t)krow * 64 + lg * 8];
    kf[c][1] = *(const short8*)&Kp[(size_t)krow * 64 + 32 + lg * 8];
  }
  // ONE drain for the whole burst (box + Q + K ~26KB/wave in flight here)
  asm volatile("s_waitcnt vmcnt(0)" ::: "memory");
  __builtin_amdgcn_sched_barrier(0);

  // ---- pass1: z = clip(box)*exp((K Q^T)/8), fp32 in regs; row sum ----
  // thread's elements: [q = q0+lr][k = n0w + c*16 + lg*4 + r]
  f32x4 z[8];
  float s1 = 0.f;
#pragma unroll
  for (int c = 0; c < 8; ++c) {
    f32x4 a = {0.f, 0.f, 0.f, 0.f};
    a = __builtin_amdgcn_mfma_f32_16x16x32_bf16(kf[c][0], qf0, a, 0, 0, 0);
    a = __builtin_amdgcn_mfma_f32_16x16x32_bf16(kf[c][1], qf1, a, 0, 0, 0);
    f32x4 e;
    e[0] = fmaxf(bx[c][0], 1e-6f) * __expf(a[0] * 0.125f);
    e[1] = fmaxf(bx[c][1], 1e-6f) * __expf(a[1] * 0.125f);
    e[2] = fmaxf(bx[c][2], 1e-6f) * __expf(a[2] * 0.125f);
    e[3] = fmaxf(bx[c][3], 1e-6f) * __expf(a[3] * 0.125f);
    s1 += (e[0] + e[1]) + (e[2] + e[3]);
    z[c] = e;
  }
  s1 += __shfl_xor(s1, 16);
  s1 += __shfl_xor(s1, 32);
  if (lg == 0) red[w][lr] = s1;
  // ---- Ext burst: 8 asm dwordx4, hidden under barrier + l1i ----
  f32x4 ex[8];
  {
    const float* ep = Ep + (size_t)lr * 512 + n0w + lg * 4;
    LDX(ex[0], ep, "");
    LDX(ex[1], ep, " offset:64");
    LDX(ex[2], ep, " offset:128");
    LDX(ex[3], ep, " offset:192");
    LDX(ex[4], ep, " offset:256");
    LDX(ex[5], ep, " offset:320");
    LDX(ex[6], ep, " offset:384");
    LDX(ex[7], ep, " offset:448");
  }
  // raw barrier: drain LDS only, keep Ext in flight
  asm volatile("s_waitcnt lgkmcnt(0)" ::: "memory");
  __builtin_amdgcn_s_barrier();
  const float l1i = 1.0f / (red[0][lr] + red[1][lr] + red[2][lr] + red[3][lr]);
  // Ext arrived; fence register consumers below the wait (rule #18)
  asm volatile("s_waitcnt vmcnt(0)" ::: "memory");
  __builtin_amdgcn_sched_barrier(0);

  // ---- pass2: z = exp(z*l1i + Ext), fp32 in regs; row sum ----
  float s2 = 0.f;
#pragma unroll
  for (int c = 0; c < 8; ++c) {
    f32x4 e;
    e[0] = __expf(z[c][0] * l1i + ex[c][0]);
    e[1] = __expf(z[c][1] * l1i + ex[c][1]);
    e[2] = __expf(z[c][2] * l1i + ex[c][2]);
    e[3] = __expf(z[c][3] * l1i + ex[c][3]);
    s2 += (e[0] + e[1]) + (e[2] + e[3]);
    z[c] = e;
  }
  s2 += __shfl_xor(s2, 16);
  s2 += __shfl_xor(s2, 32);
  if (lg == 0) red2[w][lr] = s2;
  asm volatile("s_waitcnt lgkmcnt(0)" ::: "memory");
  __builtin_amdgcn_s_barrier();
  const float l2i = 1.0f / (red2[0][lr] + red2[1][lr] + red2[2][lr] + red2[3][lr]);

  // ---- P (normalized, ONE bf16 rounding) -> per-wave LDS tile ----
#pragma unroll
  for (int c = 0; c < 8; ++c) {
    ushort4 o;
    o.x = f2bf(z[c][0] * l2i);
    o.y = f2bf(z[c][1] * l2i);
    o.z = f2bf(z[c][2] * l2i);
    o.w = f2bf(z[c][3] * l2i);
    *(ushort4*)&Pw[lr][c * 16 + lg * 4] = o;
  }
  // own-wave LDS region: same-wave ds ordering, no barrier needed
  // ---- PV: wave's partial over its 128 keys ----
  f32x4 o4[4] = {};
#pragma unroll
  for (int kc = 0; kc < 4; ++kc) {
    short8 pa = *(const short8*)&Pw[lr][kc * 32 + lg * 8];
#pragma unroll
    for (int c2 = 0; c2 < 4; ++c2) {
      short8 vf = *(const short8*)&Vt[(size_t)(c2 * 16 + lr) * 512 + n0w + kc * 32 + lg * 8];
      o4[c2] = __builtin_amdgcn_mfma_f32_16x16x32_bf16(pa, vf, o4[c2], 0, 0, 0);
    }
  }
  // partial out -> own region (aliases P tile; own-wave only)
  float* ow = (float*)wsh[w];
#pragma unroll
  for (int c2 = 0; c2 < 4; ++c2)
#pragma unroll
    for (int r = 0; r < 4; ++r)
      ow[(lg * 4 + r) * 68 + c2 * 16 + lr] = o4[c2][r];
  asm volatile("s_waitcnt lgkmcnt(0)" ::: "memory");
  __builtin_amdgcn_s_barrier();
  // cross-wave sum + vectorized store (ushort4)
  {
    const int lrow = t >> 4;
    const int d4 = (t & 15) * 4;
    f32x4 s = *(const f32x4*)&((const float*)wsh[0])[lrow * 68 + d4];
#pragma unroll
    for (int w2 = 1; w2 < 4; ++w2) {
      f32x4 p = *(const f32x4*)&((const float*)wsh[w2])[lrow * 68 + d4];
#pragma unroll
      for (int r = 0; r < 4; ++r) s[r] += p[r];
    }
    ushort4 oo;
    oo.x = f2bf(s[0]); oo.y = f2bf(s[1]); oo.z = f2bf(s[2]); oo.w = f2bf(s[3]);
    *(ushort4*)&hidden[(size_t)(b * 512 + q0 + lrow) * 512 + h * 64 + d4] = oo;
  }
}

// ---------------------------------------------------------------- kernel 3
// out = hidden[8192x512]bf16 @ WoT + bo  (fp32 out)
__global__ __launch_bounds__(256) void out_gemm(
    const unsigned short* __restrict__ hidden, const unsigned short* __restrict__ WoT,
    const float* __restrict__ bo, float* __restrict__ out) {
  const int m0 = blockIdx.x * 128, n0 = blockIdx.y * 128;
  __shared__ unsigned short Al[2][128][40];
  __shared__ unsigned short Bl[2][128][40];
  const int t = threadIdx.x;
  const int w = t >> 6, l = t & 63;
  const int lr = l & 15, lg = l >> 4;
  const int wr = (w >> 1) * 64, wc = (w & 1) * 64;
  f32x4 acc[4][4] = {};
  for (int kk = 0; kk < 512; kk += 64) {
    __syncthreads();
    {
      const int colk8 = (t & 7) * 8;
      const int kc2 = colk8 >> 5, kin2 = colk8 & 31;
#pragma unroll
      for (int p = 0; p < 4; ++p) {
        int row = p * 32 + (t >> 3);
        short8 v = *(const short8*)&hidden[(size_t)(m0 + row) * 512 + kk + colk8];
        *(short8*)&Al[kc2][row][kin2] = v;
      }
#pragma unroll
      for (int p = 0; p < 4; ++p) {
        int row = p * 32 + (t >> 3);
        short8 v = *(const short8*)&WoT[(size_t)(n0 + row) * 512 + kk + colk8];
        *(short8*)&Bl[kc2][row][kin2] = v;
      }
    }
    __syncthreads();
#pragma unroll
    for (int kc = 0; kc < 2; ++kc) {
      short8 a[4], b[4];
      const int lk = lg * 8;
#pragma unroll
      for (int i = 0; i < 4; ++i) a[i] = *(const short8*)&Al[kc][wr + i * 16 + lr][lk];
#pragma unroll
      for (int i = 0; i < 4; ++i) b[i] = *(const short8*)&Bl[kc][wc + i * 16 + lr][lk];
#pragma unroll
      for (int i = 0; i < 4; ++i)
#pragma unroll
        for (int j = 0; j < 4; ++j)
          acc[i][j] = __builtin_amdgcn_mfma_f32_16x16x32_bf16(a[i], b[j], acc[i][j], 0, 0, 0);
    }
  }
#pragma unroll
  for (int j = 0; j < 4; ++j) {
    const int col = n0 + wc + j * 16 + lr;
    const float bb = bo[col];
#pragma unroll
    for (int i = 0; i < 4; ++i)
#pragma unroll
      for (int r = 0; r < 4; ++r)
        out[(size_t)(m0 + wr + i * 16 + lg * 4 + r) * 512 + col] = acc[i][j][r] + bb;
  }
}

// ---------------------------------------------------------------- launch
extern "C" void kernel_launch(void* const* d_in, const int* in_sizes, int n_in,
                              void* d_out, int out_size, void* d_ws, size_t ws_size,
                              hipStream_t stream) {
  const float* queries = (const float*)d_in[0];
  const float* keys = (const float*)d_in[1];
  const float* values = (const float*)d_in[2];
  const float* box = (const float*)d_in[3];
  const float* ext = (const float*)d_in[4];
  const float* Wq = (const float*)d_in[5];
  const float* bq = (const float*)d_in[6];
  const float* Wk = (const float*)d_in[7];
  const float* bk = (const float*)d_in[8];
  const float* Wv = (const float*)d_in[9];
  const float* bv = (const float*)d_in[10];
  const float* Wo = (const float*)d_in[11];
  const float* bo = (const float*)d_in[12];
  float* out = (float*)d_out;

  char* ws = (char*)d_ws;
  unsigned short* q_ws = (unsigned short*)(ws);
  unsigned short* k_ws = (unsigned short*)(ws + 8u * 1024 * 1024);
  unsigned short* vt_ws = (unsigned short*)(ws + 16u * 1024 * 1024);
  unsigned short* hidden = (unsigned short*)(ws + 24u * 1024 * 1024);
  unsigned short* wt = (unsigned short*)(ws + 32u * 1024 * 1024);  // 4 x 512KB

  wprep<<<dim3(8, 8, 4), 256, 0, stream>>>(Wq, Wk, Wv, Wo, wt);
  qkv_gemm<<<dim3(64, 4, 3), 256, 0, stream>>>(queries, keys, values, wt, bq, bk, bv,
                                               q_ws, k_ws, vt_ws);
  attn_kernel<<<dim3(4096), 256, 0, stream>>>(q_ws, k_ws, vt_ws, box, ext, hidden);
  out_gemm<<<dim3(64, 4), 256, 0, stream>>>(hidden, wt + 3u * 512 * 512, bo, out);
}